// Round 2
// baseline (30125.211 us; speedup 1.0000x reference)
//
#include <hip/hip_runtime.h>

#define BB 128
#define TT 256
#define HH 512

__device__ __forceinline__ float fsig(float x) { return 1.f / (1.f + __expf(-x)); }

// Step kernel v2.
// Block: 256 threads = 32 "rows" (8 hidden units x 4 gate banks) x 8 batch-groups(4 each).
// gates[b][g] = bias[g] + x_t[b,:] @ wih[g,:] + h_prev[b,:] @ whh[g,:]
// W is streamed per-thread from global (L1/L2-cached sequential row streams).
// A operand (x_t then h_prev) is LDS-staged in chunks of <=256 K, reads are broadcasts.
// Epilogue: wave-local __shfl gate gather -> c/h update.
template <int K1>
__global__ __launch_bounds__(256, 2) void lstm_step2(
    int s, int reverse_mask,
    const float* __restrict__ xF, const float* __restrict__ xB,
    long x_bstr, long x_tstr,
    const float* __restrict__ wihF, const float* __restrict__ wihB,
    const float* __restrict__ whhF, const float* __restrict__ whhB,
    const float* __restrict__ bF, const float* __restrict__ bB,
    const float* __restrict__ h_prev, float* __restrict__ h_next,
    float* __restrict__ c_state, float* __restrict__ h_out) {
  constexpr int NX = (K1 + 255) / 256;  // x chunks
  constexpr int NCH = NX + 2;           // + two h chunks (512)
  const int d = blockIdx.y;
  const int t = ((reverse_mask >> d) & 1) ? (TT - 1 - s) : s;
  const float* xin = (d ? xB : xF) + (long)t * x_tstr;
  const float* wih = d ? wihB : wihF;
  const float* whh = d ? whhB : whhF;
  const float* bias = d ? bB : bF;
  const float* hp = h_prev + (long)d * (BB * HH);
  float* hn = h_next + (long)d * (BB * HH);
  float* cs = c_state + (long)d * (BB * HH);

  const int rt = blockIdx.x & 63;  // 64 row tiles (8 units each)
  const int bt = blockIdx.x >> 6;  // 4 batch tiles (32 each)
  const int j0 = rt * 8;
  const int b0 = bt * 32;

  const int tid = threadIdx.x;
  const int rr = tid & 31;          // row within block
  const int jj = rr & 7;            // unit within tile
  const int q = rr >> 3;            // gate bank 0..3 (i,f,g,o)
  const int bg = tid >> 5;          // batch group 0..7
  const int grow = q * HH + j0 + jj;

  __shared__ float sh[32 * 256];  // [32 batch][256 K], row stride 256 floats

  float acc[4] = {0.f, 0.f, 0.f, 0.f};
  const float bi = bias[grow];

  float4 rg[8];
  const float* wr_cur = nullptr;
  int kt_cur = 0;

  auto ldchunk = [&](int c) {
    const float* Asrc;
    long bstr;
    int kbase, kt;
    if (c < NX) {
      kt = (K1 - c * 256 < 256) ? (K1 - c * 256) : 256;
      kbase = c * 256;
      Asrc = xin;
      bstr = x_bstr;
      wr_cur = wih + (long)grow * K1 + kbase;
    } else {
      kt = 256;
      kbase = (c - NX) * 256;
      Asrc = hp;
      bstr = HH;
      wr_cur = whh + (long)grow * HH + kbase;
    }
    const int kt4 = kt >> 2;
    const int nf4 = kt4 * 32;
    const int ktl = (kt == 256) ? 6 : 4;  // kt in {256, 64}
#pragma unroll
    for (int i = 0; i < 8; ++i) {
      int ft = tid + (i << 8);
      if (ft < nf4) {
        int row = ft >> ktl;
        int kc = ft & (kt4 - 1);
        rg[i] = *(const float4*)(Asrc + (long)(b0 + row) * bstr + kbase + (kc << 2));
      }
    }
    kt_cur = kt;
  };

  ldchunk(0);
  for (int c = 0; c < NCH; ++c) {
    const float* wr_c = wr_cur;
    const int kt_c = kt_cur;
    __syncthreads();  // previous chunk's readers done
    {
      const int kt4 = kt_c >> 2;
      const int nf4 = kt4 * 32;
      const int ktl = (kt_c == 256) ? 6 : 4;
#pragma unroll
      for (int i = 0; i < 8; ++i) {
        int ft = tid + (i << 8);
        if (ft < nf4)
          ((float4*)sh)[((ft >> ktl) << 6) + (ft & (kt4 - 1))] = rg[i];
      }
    }
    if (c + 1 < NCH) ldchunk(c + 1);  // prefetch next chunk into regs (overlaps compute)
    __syncthreads();

    const float* shr = sh + (bg << 2) * 256;
#pragma unroll 4
    for (int kk = 0; kk < kt_c; kk += 4) {
      float4 w4 = *(const float4*)(wr_c + kk);
      float4 a0 = *(const float4*)(shr + kk);
      float4 a1 = *(const float4*)(shr + 256 + kk);
      float4 a2 = *(const float4*)(shr + 512 + kk);
      float4 a3 = *(const float4*)(shr + 768 + kk);
      acc[0] = fmaf(a0.x, w4.x, acc[0]);
      acc[0] = fmaf(a0.y, w4.y, acc[0]);
      acc[0] = fmaf(a0.z, w4.z, acc[0]);
      acc[0] = fmaf(a0.w, w4.w, acc[0]);
      acc[1] = fmaf(a1.x, w4.x, acc[1]);
      acc[1] = fmaf(a1.y, w4.y, acc[1]);
      acc[1] = fmaf(a1.z, w4.z, acc[1]);
      acc[1] = fmaf(a1.w, w4.w, acc[1]);
      acc[2] = fmaf(a2.x, w4.x, acc[2]);
      acc[2] = fmaf(a2.y, w4.y, acc[2]);
      acc[2] = fmaf(a2.z, w4.z, acc[2]);
      acc[2] = fmaf(a2.w, w4.w, acc[2]);
      acc[3] = fmaf(a3.x, w4.x, acc[3]);
      acc[3] = fmaf(a3.y, w4.y, acc[3]);
      acc[3] = fmaf(a3.z, w4.z, acc[3]);
      acc[3] = fmaf(a3.w, w4.w, acc[3]);
    }
  }

  // epilogue: gather i,f,g,o for (unit jj, batch) from lanes (lane&32)|q'*8|jj
  const int lane = tid & 63;
  const int base = (lane & 32) | jj;
#pragma unroll
  for (int u = 0; u < 4; ++u) {
    float g = acc[u] + bi;
    float gi = __shfl(g, base);
    float gf = __shfl(g, base + 8);
    float gg = __shfl(g, base + 16);
    float go = __shfl(g, base + 24);
    if (q == 0) {
      const int b = b0 + (bg << 2) + u;
      const long idx = (long)b * HH + j0 + jj;
      float cn = fsig(gf) * cs[idx] + fsig(gi) * tanhf(gg);
      cs[idx] = cn;
      float hv = fsig(go) * tanhf(cn);
      hn[idx] = hv;
      if (h_out)
        h_out[(long)b * (TT * 1024) + (long)t * 1024 + d * 512 + j0 + jj] = hv;
    }
  }
}

__global__ void fc_kernel(const float* __restrict__ h1f, const float* __restrict__ h1b,
                          const float* __restrict__ fcw, const float* __restrict__ fcb,
                          float* __restrict__ out) {
  const int b = blockIdx.x;
  const int lane = threadIdx.x;
  float s = 0.f;
  for (int j = lane; j < HH; j += 64) {
    s += h1f[(long)b * HH + j] * fcw[j];
    s += h1b[(long)b * HH + j] * fcw[HH + j];
  }
#pragma unroll
  for (int off = 32; off; off >>= 1) s += __shfl_down(s, off);
  if (lane == 0) out[b] = s + fcb[0];
}

extern "C" void kernel_launch(void* const* d_in, const int* in_sizes, int n_in,
                              void* d_out, int out_size, void* d_ws, size_t ws_size,
                              hipStream_t stream) {
  const float* x     = (const float*)d_in[0];
  const float* wih0f = (const float*)d_in[1];
  const float* whh0f = (const float*)d_in[2];
  const float* b0f   = (const float*)d_in[3];
  const float* wih0b = (const float*)d_in[4];
  const float* whh0b = (const float*)d_in[5];
  const float* b0b   = (const float*)d_in[6];
  const float* wih1f = (const float*)d_in[7];
  const float* whh1f = (const float*)d_in[8];
  const float* b1f   = (const float*)d_in[9];
  const float* wih1b = (const float*)d_in[10];
  const float* whh1b = (const float*)d_in[11];
  const float* b1b   = (const float*)d_in[12];
  const float* fcw   = (const float*)d_in[13];
  const float* fcb   = (const float*)d_in[14];
  float* out = (float*)d_out;

  float* ws  = (float*)d_ws;
  float* hA  = ws;               // [2][128][512]
  float* hB  = hA + 2 * BB * HH; // [2][128][512]
  float* cS  = hB + 2 * BB * HH; // [2][128][512]
  float* zb  = cS + 2 * BB * HH; // [128][512] zeros
  float* cz  = zb + BB * HH;     // [128][512] zeros
  float* h1b = cz + BB * HH;     // [128][512]
  float* h0  = h1b + BB * HH;    // [128][256][1024]  (128 MB)

  hipMemsetAsync(hA, 0, 2 * BB * HH * sizeof(float), stream);
  hipMemsetAsync(cS, 0, 2 * BB * HH * sizeof(float), stream);
  hipMemsetAsync(zb, 0, BB * HH * sizeof(float), stream);
  hipMemsetAsync(cz, 0, BB * HH * sizeof(float), stream);

  // layer 0: fwd + bwd concurrently (grid.y = dir), reverse_mask = 0b10
  for (int s = 0; s < TT; ++s) {
    const float* hp = (s & 1) ? hB : hA;
    float* hn = (s & 1) ? hA : hB;
    lstm_step2<64><<<dim3(256, 2), 256, 0, stream>>>(
        s, 2, x, x, (long)TT * 64, 64,
        wih0f, wih0b, whh0f, whh0b, b0f, b0b,
        hp, hn, cS, h0);
  }

  hipMemsetAsync(hA, 0, 2 * BB * HH * sizeof(float), stream);
  hipMemsetAsync(cS, 0, 2 * BB * HH * sizeof(float), stream);

  // layer 1 forward over h0 [B][T][1024]
  for (int s = 0; s < TT; ++s) {
    const float* hp = (s & 1) ? hB : hA;
    float* hn = (s & 1) ? hA : hB;
    lstm_step2<1024><<<dim3(256, 1), 256, 0, stream>>>(
        s, 0, h0, nullptr, (long)TT * 1024, 1024,
        wih1f, nullptr, whh1f, nullptr, b1f, nullptr,
        hp, hn, cS, nullptr);
  }

  // layer 1 backward: only its t = T-1 step matters (h0=c0=0)
  lstm_step2<1024><<<dim3(256, 1), 256, 0, stream>>>(
      0, 1, h0, nullptr, (long)TT * 1024, 1024,
      wih1b, nullptr, whh1b, nullptr, b1b, nullptr,
      zb, h1b, cz, nullptr);

  // fc on [h1f_final ; h1b_t255]; after 256 steps final h is in hA (dir 0)
  fc_kernel<<<dim3(BB), dim3(64), 0, stream>>>(hA, h1b, fcw, fcb, out);
}

// Round 3
// 8805.354 us; speedup vs baseline: 3.4212x; 3.4212x over previous
//
#include <hip/hip_runtime.h>

#define HB 65536  // 128*512

typedef unsigned short u16;
typedef __attribute__((ext_vector_type(8))) short bf16x8;
typedef __attribute__((ext_vector_type(8))) _Float16 f16x8;
typedef __attribute__((ext_vector_type(4))) float f32x4;

__device__ __forceinline__ float fsig(float x) { return 1.f / (1.f + __expf(-x)); }
__device__ __forceinline__ float ftanh(float x) {
  float e = __expf(2.f * x);
  return 1.f - 2.f / (e + 1.f);
}
__device__ __forceinline__ u16 f2bf(float f) {
  unsigned u = __builtin_bit_cast(unsigned, f);
  return (u16)((u + 0x7FFFu + ((u >> 16) & 1)) >> 16);
}
__device__ __forceinline__ float bf2f(u16 h) {
  unsigned u = ((unsigned)h) << 16;
  return __builtin_bit_cast(float, u);
}
__device__ __forceinline__ u16 f2h(float f) {
  _Float16 h = (_Float16)f;
  return __builtin_bit_cast(u16, h);
}

// ---- pack weights [2048][K] fp32 -> fragment-major hi/lo ----
// dst layout: [rt 128][kt K/32][hl 2][lane 64][e 8] u16
// packed row r (0..15): bank=r>>2, uoff=r&3 -> gate row = bank*512 + rt*4 + uoff
// lane l: r=l&15, k0 = kt*32 + (l>>4)*8
template <bool F16>
__global__ void pack_w(const float* __restrict__ W, u16* __restrict__ dst, int K) {
  int NKT = K >> 5;
  long gid = (long)blockIdx.x * 256 + threadIdx.x;
  long total = (long)128 * NKT * 64;
  if (gid >= total) return;
  int lane = gid & 63;
  int kt = (gid >> 6) % NKT;
  int rt = (gid >> 6) / NKT;
  int r = lane & 15;
  int grow = (r >> 2) * 512 + rt * 4 + (r & 3);
  int k0 = kt * 32 + (lane >> 4) * 8;
  long base = ((long)(rt * NKT + kt) * 2) * 512 + lane * 8;
#pragma unroll
  for (int e = 0; e < 8; ++e) {
    float w = W[(long)grow * K + k0 + e];
    u16 hi, lo;
    if (F16) {
      _Float16 h = (_Float16)w;
      hi = __builtin_bit_cast(u16, h);
      _Float16 l2 = (_Float16)(w - (float)h);
      lo = __builtin_bit_cast(u16, l2);
    } else {
      hi = f2bf(w);
      lo = f2bf(w - bf2f(hi));
    }
    dst[base + e] = hi;
    dst[base + 512 + e] = lo;
  }
}

// x [B=128][T=256][64] fp32 -> xpack f16 [t][b][64]
__global__ void pack_x(const float* __restrict__ x, u16* __restrict__ xp) {
  long gid = (long)blockIdx.x * 256 + threadIdx.x;
  if (gid >= 128L * 256 * 64) return;
  int k = gid & 63;
  long bt = gid >> 6;
  int t = bt & 255;
  int b = bt >> 8;
  float v = x[((long)b * 256 + t) * 64 + k];
  xp[((long)t * 128 + b) * 64 + k] = f2h(v);
}

// biases -> [4 src][128 rt][16 r] with r: bank=r>>2, uoff=r&3
__global__ void pack_bias(const float* __restrict__ b0f, const float* __restrict__ b0b,
                          const float* __restrict__ b1f, const float* __restrict__ b1b,
                          float* __restrict__ bp) {
  int gid = blockIdx.x * 256 + threadIdx.x;
  if (gid >= 8192) return;
  int src = gid >> 11;
  int idx = gid & 2047;
  int rt = idx >> 4, rr = idx & 15;
  int grow = (rr >> 2) * 512 + rt * 4 + (rr & 3);
  const float* B = (src == 0) ? b0f : (src == 1) ? b0b : (src == 2) ? b1f : b1b;
  bp[gid] = B[grow];
}

// ---- one LSTM timestep, MFMA split-precision ----
// grid: dir_count*256 blocks, 256 thr (4 waves). Block: 2 rowtiles x 2 batchtiles.
// wave C-tile: 16 packed rows (4 units x 4 banks) x 16 batches.
__global__ __launch_bounds__(256) void lstm_mfma_step(
    int s, int revmask, int dir_blocks, int KXkt,
    long xb_stride, long xt_stride,
    const u16* __restrict__ xsrc,
    const u16* __restrict__ wxF, const u16* __restrict__ wxB,
    const u16* __restrict__ whF, const u16* __restrict__ whB,
    const float* __restrict__ biasP,
    const u16* __restrict__ hprev, u16* __restrict__ hnext,
    float* __restrict__ cstate, u16* __restrict__ h0arch) {
  const int bx = blockIdx.x;
  const int dir = bx / dir_blocks;
  const int rb = bx % dir_blocks;
  const int rg = rb >> 2, bg = rb & 3;
  const int w = threadIdx.x >> 6, l = threadIdx.x & 63;
  const int rowt = rg * 2 + (w >> 1);   // 0..127
  const int bt = bg * 2 + (w & 1);      // 0..7
  const int b0 = bt * 16;
  const int c = l & 15, q = l >> 4;
  const int t = ((revmask >> dir) & 1) ? (255 - s) : s;

  const u16* wx = dir ? wxB : wxF;
  const u16* wh = dir ? whB : whF;
  const u16* xr = xsrc + (long)t * xt_stride + (long)(b0 + c) * xb_stride + q * 8;
  const u16* hp_hi = hprev + (long)dir * 2 * HB + (long)(b0 + c) * 512 + q * 8;
  const u16* hp_lo = hp_hi + HB;

  f32x4 acc = {0.f, 0.f, 0.f, 0.f};

  // f16 2-product: static input projection (x or h0)
  const u16* ax = wx + (long)rowt * KXkt * 1024 + l * 8;
#pragma unroll 4
  for (int kt = 0; kt < KXkt; ++kt) {
    f16x8 ahi = *reinterpret_cast<const f16x8*>(ax);
    f16x8 alo = *reinterpret_cast<const f16x8*>(ax + 512);
    f16x8 bx8 = *reinterpret_cast<const f16x8*>(xr + kt * 32);
    acc = __builtin_amdgcn_mfma_f32_16x16x32_f16(ahi, bx8, acc, 0, 0, 0);
    acc = __builtin_amdgcn_mfma_f32_16x16x32_f16(alo, bx8, acc, 0, 0, 0);
    ax += 1024;
  }
  // bf16 3-product: recurrent h part (K=512 -> 16 ktiles)
  const u16* ah = wh + (long)rowt * 16 * 1024 + l * 8;
#pragma unroll 4
  for (int kt = 0; kt < 16; ++kt) {
    bf16x8 ahi = *reinterpret_cast<const bf16x8*>(ah);
    bf16x8 alo = *reinterpret_cast<const bf16x8*>(ah + 512);
    bf16x8 bhi = *reinterpret_cast<const bf16x8*>(hp_hi + kt * 32);
    bf16x8 blo = *reinterpret_cast<const bf16x8*>(hp_lo + kt * 32);
    acc = __builtin_amdgcn_mfma_f32_16x16x32_bf16(ahi, bhi, acc, 0, 0, 0);
    acc = __builtin_amdgcn_mfma_f32_16x16x32_bf16(alo, bhi, acc, 0, 0, 0);
    acc = __builtin_amdgcn_mfma_f32_16x16x32_bf16(ahi, blo, acc, 0, 0, 0);
    ah += 1024;
  }

  // epilogue: C[row=(q*4+i)][col=c] ; bank=q, unit=rowt*4+i
  const float* bp = biasP + ((long)dir * 128 + rowt) * 16 + q * 4;
  float pre[4];
#pragma unroll
  for (int i = 0; i < 4; ++i) pre[i] = acc[i] + bp[i];

  float* cbase = cstate + (long)dir * HB;
  u16* hn_hi = hnext + (long)dir * 2 * HB;
  u16* hn_lo = hn_hi + HB;
  const int b = b0 + c;
#pragma unroll
  for (int i = 0; i < 4; ++i) {
    float gI = __shfl(pre[i], c);
    float gF = __shfl(pre[i], c + 16);
    float gG = __shfl(pre[i], c + 32);
    float gO = __shfl(pre[i], c + 48);
    int u = rowt * 4 + i;
    long cidx = (long)u * 128 + b;
    float co = cbase[cidx];
    float cn = fsig(gF) * co + fsig(gI) * ftanh(gG);
    float hv = fsig(gO) * ftanh(cn);
    if (q == 0) {
      cbase[cidx] = cn;
      u16 hh = f2bf(hv);
      hn_hi[(long)b * 512 + u] = hh;
      hn_lo[(long)b * 512 + u] = f2bf(hv - bf2f(hh));
      if (h0arch)
        h0arch[((long)t * 128 + b) * 1024 + dir * 512 + u] = f2h(hv);
    }
  }
}

__global__ void fc_kernel(const u16* __restrict__ h1f, const u16* __restrict__ h1b,
                          const float* __restrict__ fcw, const float* __restrict__ fcb,
                          float* __restrict__ out) {
  const int b = blockIdx.x;
  const int lane = threadIdx.x;
  float s = 0.f;
  for (int j = lane; j < 512; j += 64) {
    float hf = bf2f(h1f[(long)b * 512 + j]) + bf2f(h1f[HB + (long)b * 512 + j]);
    float hbk = bf2f(h1b[(long)b * 512 + j]) + bf2f(h1b[HB + (long)b * 512 + j]);
    s += hf * fcw[j] + hbk * fcw[512 + j];
  }
#pragma unroll
  for (int off = 32; off; off >>= 1) s += __shfl_down(s, off);
  if (lane == 0) out[b] = s + fcb[0];
}

extern "C" void kernel_launch(void* const* d_in, const int* in_sizes, int n_in,
                              void* d_out, int out_size, void* d_ws, size_t ws_size,
                              hipStream_t stream) {
  const float* x     = (const float*)d_in[0];
  const float* wih0f = (const float*)d_in[1];
  const float* whh0f = (const float*)d_in[2];
  const float* b0f   = (const float*)d_in[3];
  const float* wih0b = (const float*)d_in[4];
  const float* whh0b = (const float*)d_in[5];
  const float* b0b   = (const float*)d_in[6];
  const float* wih1f = (const float*)d_in[7];
  const float* whh1f = (const float*)d_in[8];
  const float* b1f   = (const float*)d_in[9];
  const float* wih1b = (const float*)d_in[10];
  const float* whh1b = (const float*)d_in[11];
  const float* b1b   = (const float*)d_in[12];
  const float* fcw   = (const float*)d_in[13];
  const float* fcb   = (const float*)d_in[14];
  float* out = (float*)d_out;

  char* p = (char*)d_ws;
  auto alloc = [&](size_t bytes) {
    char* r = p;
    p += (bytes + 255) & ~(size_t)255;
    return r;
  };
  u16* xpack   = (u16*)alloc(128L * 256 * 64 * 2);        // 4.2 MB
  u16* h0arch  = (u16*)alloc(256L * 128 * 1024 * 2);      // 67 MB
  u16* wih0f_p = (u16*)alloc(128L * 2 * 2 * 512 * 2);     // 0.5 MB
  u16* wih0b_p = (u16*)alloc(128L * 2 * 2 * 512 * 2);
  u16* whh0f_p = (u16*)alloc(128L * 16 * 2 * 512 * 2);    // 4.2 MB
  u16* whh0b_p = (u16*)alloc(128L * 16 * 2 * 512 * 2);
  u16* wih1f_p = (u16*)alloc(128L * 32 * 2 * 512 * 2);    // 8.4 MB
  u16* whh1f_p = (u16*)alloc(128L * 16 * 2 * 512 * 2);
  u16* wih1b_p = (u16*)alloc(128L * 32 * 2 * 512 * 2);
  u16* whh1b_p = (u16*)alloc(128L * 16 * 2 * 512 * 2);
  float* biasP = (float*)alloc(8192 * 4);
  u16* hl0     = (u16*)alloc(2L * 2 * 2 * HB * 2);        // [par][dir][hl][..]
  u16* hl1     = (u16*)alloc(2L * 2 * HB * 2);            // [par][hl][..]
  u16* hz      = (u16*)alloc(2L * HB * 2);
  u16* h1bout  = (u16*)alloc(2L * HB * 2);
  float* c0    = (float*)alloc(2L * HB * 4);
  float* c1    = (float*)alloc((long)HB * 4);
  float* czb   = (float*)alloc((long)HB * 4);

  // packs (one-time, parallel)
  pack_w<true><<<64, 256, 0, stream>>>(wih0f, wih0f_p, 64);
  pack_w<true><<<64, 256, 0, stream>>>(wih0b, wih0b_p, 64);
  pack_w<false><<<512, 256, 0, stream>>>(whh0f, whh0f_p, 512);
  pack_w<false><<<512, 256, 0, stream>>>(whh0b, whh0b_p, 512);
  pack_w<true><<<1024, 256, 0, stream>>>(wih1f, wih1f_p, 1024);
  pack_w<false><<<512, 256, 0, stream>>>(whh1f, whh1f_p, 512);
  pack_w<true><<<1024, 256, 0, stream>>>(wih1b, wih1b_p, 1024);
  pack_w<false><<<512, 256, 0, stream>>>(whh1b, whh1b_p, 512);
  pack_x<<<8192, 256, 0, stream>>>(x, xpack);
  pack_bias<<<32, 256, 0, stream>>>(b0f, b0b, b1f, b1b, biasP);

  hipMemsetAsync(hl0, 0, 2L * 2 * HB * 2, stream);  // parity 0
  hipMemsetAsync(hl1, 0, 2L * HB * 2, stream);      // parity 0
  hipMemsetAsync(hz, 0, 2L * HB * 2, stream);
  hipMemsetAsync(c0, 0, 2L * HB * 4, stream);
  hipMemsetAsync(c1, 0, (long)HB * 4, stream);
  hipMemsetAsync(czb, 0, (long)HB * 4, stream);

  // layer 0: both dirs, 256 steps
  for (int s = 0; s < 256; ++s) {
    u16* hp = hl0 + (long)(s & 1) * 2 * 2 * HB;
    u16* hn = hl0 + (long)((s & 1) ^ 1) * 2 * 2 * HB;
    lstm_mfma_step<<<512, 256, 0, stream>>>(
        s, /*revmask*/2, /*dir_blocks*/256, /*KXkt*/2,
        64, 128L * 64, xpack,
        wih0f_p, wih0b_p, whh0f_p, whh0b_p, biasP,
        hp, hn, c0, h0arch);
  }
  // layer 1 forward: 256 steps over h0
  for (int s = 0; s < 256; ++s) {
    u16* hp = hl1 + (long)(s & 1) * 2 * HB;
    u16* hn = hl1 + (long)((s & 1) ^ 1) * 2 * HB;
    lstm_mfma_step<<<256, 256, 0, stream>>>(
        s, 0, 256, /*KXkt*/32,
        1024, 128L * 1024, h0arch,
        wih1f_p, nullptr, whh1f_p, nullptr, biasP + 4096,
        hp, hn, c1, nullptr);
  }
  // layer 1 backward: only t=255 matters (zero initial state)
  lstm_mfma_step<<<256, 256, 0, stream>>>(
      255, 0, 256, 32,
      1024, 128L * 1024, h0arch,
      wih1b_p, nullptr, whh1b_p, nullptr, biasP + 6144,
      hz, h1bout, czb, nullptr);

  // fc: final l1f h is in parity 0 after 256 steps
  fc_kernel<<<128, 64, 0, stream>>>(hl1, h1bout, fcw, fcb, out);
}